// Round 8
// baseline (326.462 us; speedup 1.0000x reference)
//
#include <hip/hip_runtime.h>
#include <math.h>

// Problem constants
#define BN 32768
#define DN 512
#define SN 32
#define LN 8
#define KN 256
#define N2 65536   // 2*BN
#define SPLIT 8    // blocks per group in k1/k3

typedef __attribute__((ext_vector_type(8))) short bf16x8;
typedef __attribute__((ext_vector_type(4))) float f32x4;

// workspace layout (byte offsets)
#define OFF_XBF     0ull            // ushort[N2*DN]            67108864
#define OFF_PART    67108864ull     // float[SPLIT*KN*DN]        4194304
#define OFF_SUMS    71303168ull     // float[KN*DN]               524288
#define OFF_CENTB   71827456ull     // ushort[KN*DN]              262144
#define OFF_GID     72089600ull     // int[BN]                    131072
#define OFF_PERM    72220672ull     // int[BN]                    131072
#define OFF_BASE    72351744ull     // int[KN+1]
#define OFF_OFFW    72352772ull     // int[KN]
#define OFF_COUNTS  72353796ull     // int[KN]
#define OFF_SUMQ    72354820ull     // float[KN]
#define OFF_INVD    72355844ull     // float[KN]
#define OFF_LOSS    72356868ull     // float[1]
#define ZERO_OFF    OFF_COUNTS
#define ZERO_BYTES  (72356872ull - OFF_COUNTS)

__device__ __forceinline__ float atomAddF(float* p, float v) {
  return unsafeAtomicAdd(p, v);   // hw global_atomic_add_f32
}

__device__ __forceinline__ ushort f2bf(float x) {
  union { float f; unsigned u; } v; v.f = x;
  unsigned u = v.u;
  unsigned r = (u + 0x7fffu + ((u >> 16) & 1u)) >> 16;  // RNE
  return (ushort)r;
}

__device__ __forceinline__ float bf2f(ushort x) {
  union { unsigned u; float f; } v; v.u = ((unsigned)x) << 16;
  return v.f;
}

// async 16B/lane global->LDS DMA (lands at lds base + lane*16)
__device__ __forceinline__ void async16(const void* g, void* l) {
  __builtin_amdgcn_global_load_lds(
      (const __attribute__((address_space(1))) unsigned int*)g,
      (__attribute__((address_space(3))) unsigned int*)l, 16, 0, 0);
}

// ---- k0a: gid + counts histogram ----
__global__ __launch_bounds__(256) void k0_gid(const int* __restrict__ subject,
    const int* __restrict__ labels, int* __restrict__ gid, int* __restrict__ counts) {
  __shared__ int hist[KN];
  hist[threadIdx.x] = 0;
  __syncthreads();
  const int b0 = blockIdx.x * 1024;
  for (int i = threadIdx.x; i < 1024; i += 256) {
    int b = b0 + i;
    int g = subject[b] * LN + labels[b];
    gid[b] = g;
    atomicAdd(&hist[g], 1);
  }
  __syncthreads();
  if (hist[threadIdx.x]) atomicAdd(&counts[threadIdx.x], 2 * hist[threadIdx.x]);
}

// ---- k0b: exclusive scan of per-group row counts -> base, offw ----
__global__ __launch_bounds__(256) void k0b_scan(const int* __restrict__ counts,
    int* __restrict__ base, int* __restrict__ offw) {
  __shared__ int sh[KN];
  const int t = threadIdx.x;
  const int h = counts[t] >> 1;   // rows (not x2 views)
  sh[t] = h;
  __syncthreads();
  for (int d = 1; d < 256; d <<= 1) {
    int add = (t >= d) ? sh[t - d] : 0;
    __syncthreads();
    sh[t] += add;
    __syncthreads();
  }
  const int excl = sh[t] - h;
  base[t] = excl;
  offw[t] = excl;
  if (t == 255) base[256] = sh[255];
}

// ---- k0c: counting-sort scatter -> perm, LDS-aggregated ----
// 32 blocks x 1024 rows; local rank via LDS atomic return value (within-group
// order is irrelevant downstream), ONE global atomic per (block, group).
__global__ __launch_bounds__(256) void k0c_scatter(const int* __restrict__ gid,
    int* __restrict__ offw, int* __restrict__ perm) {
  __shared__ int lhist[KN];
  __shared__ int lbase[KN];
  const int t = threadIdx.x;
  const int b0 = blockIdx.x * 1024;
  lhist[t] = 0;
  __syncthreads();
  int g[4], lr[4];
#pragma unroll
  for (int k = 0; k < 4; ++k) {
    g[k] = gid[b0 + k * 256 + t];
    lr[k] = atomicAdd(&lhist[g[k]], 1);
  }
  __syncthreads();
  const int h = lhist[t];
  if (h) lbase[t] = atomicAdd(&offw[t], h);
  __syncthreads();
#pragma unroll
  for (int k = 0; k < 4; ++k) {
    perm[lbase[g[k]] + lr[k]] = b0 + k * 256 + t;
  }
}

// ---- k1: sorted segment-reduce group sums + f32->bf16 conversion ----
// Wave-parallel: each wave owns an independent row stream (32 streams/group).
__global__ __launch_bounds__(256) void k1_sums(const float* __restrict__ X,
    const int* __restrict__ perm, const int* __restrict__ base,
    ushort* __restrict__ Xb, float* __restrict__ partial) {
  __shared__ float buf[4 * 512];
  const int g = blockIdx.x >> 3;
  const int s = blockIdx.x & (SPLIT - 1);
  const int t = threadIdx.x;
  const int w = t >> 6;
  const int lane = t & 63;
  const int start = base[g], end = base[g + 1];
  const int vs = s * 4 + w;              // stream 0..31

  float4 a0 = {0.f, 0.f, 0.f, 0.f};
  float4 a1 = {0.f, 0.f, 0.f, 0.f};

  int i = start + vs;
  if (i < end) {
    int idx = perm[i];
    const float* bp = X + (size_t)idx * 1024 + lane * 4;
    float4 x0 = *(const float4*)(bp);
    float4 x1 = *(const float4*)(bp + 256);
    float4 x2 = *(const float4*)(bp + 512);
    float4 x3 = *(const float4*)(bp + 768);
    while (true) {
      const int inext = i + 32;
      int idxn = idx;
      float4 y0 = x0, y1 = x1, y2 = x2, y3 = x3;
      if (inext < end) {
        idxn = perm[inext];
        const float* bn = X + (size_t)idxn * 1024 + lane * 4;
        y0 = *(const float4*)(bn);
        y1 = *(const float4*)(bn + 256);
        y2 = *(const float4*)(bn + 512);
        y3 = *(const float4*)(bn + 768);
      }
      a0.x += x0.x + x2.x; a0.y += x0.y + x2.y;
      a0.z += x0.z + x2.z; a0.w += x0.w + x2.w;
      a1.x += x1.x + x3.x; a1.y += x1.y + x3.y;
      a1.z += x1.z + x3.z; a1.w += x1.w + x3.w;
      ushort* xb0 = Xb + (size_t)idx * DN + lane * 4;
      ushort* xb1 = Xb + (size_t)(idx + BN) * DN + lane * 4;
      *(ushort4*)(xb0)       = (ushort4){f2bf(x0.x), f2bf(x0.y), f2bf(x0.z), f2bf(x0.w)};
      *(ushort4*)(xb0 + 256) = (ushort4){f2bf(x1.x), f2bf(x1.y), f2bf(x1.z), f2bf(x1.w)};
      *(ushort4*)(xb1)       = (ushort4){f2bf(x2.x), f2bf(x2.y), f2bf(x2.z), f2bf(x2.w)};
      *(ushort4*)(xb1 + 256) = (ushort4){f2bf(x3.x), f2bf(x3.y), f2bf(x3.z), f2bf(x3.w)};
      if (inext >= end) break;
      i = inext; idx = idxn; x0 = y0; x1 = y1; x2 = y2; x3 = y3;
    }
  }
  *(float4*)&buf[w * 512 + lane * 4] = a0;
  *(float4*)&buf[w * 512 + 256 + lane * 4] = a1;
  __syncthreads();
  if (t < 128) {
    float4 r = {0.f, 0.f, 0.f, 0.f};
#pragma unroll
    for (int ww = 0; ww < 4; ++ww) {
      float4 v = *(float4*)&buf[ww * 512 + t * 4];
      r.x += v.x; r.y += v.y; r.z += v.z; r.w += v.w;
    }
    *(float4*)&partial[((size_t)s * KN + g) * DN + t * 4] = r;
  }
}

// ---- k1b: reduce split partials -> sums + bf16 centroids ----
__global__ __launch_bounds__(256) void k1b_cent(const float* __restrict__ partial,
    const int* __restrict__ counts, float* __restrict__ sums,
    ushort* __restrict__ centB) {
  const int i = blockIdx.x * 256 + threadIdx.x;   // over KN*DN, [g][d]
  const int g = i >> 9;
  float ss = 0.f;
#pragma unroll
  for (int s = 0; s < SPLIT; ++s) ss += partial[(size_t)s * (KN * DN) + i];
  sums[i] = ss;
  centB[i] = f2bf(ss / (float)counts[g]);
}

// ---- k3: group-per-block distance^0.25 accumulation, 1 atomic/block ----
__global__ __launch_bounds__(256) void k3_dist(const ushort* __restrict__ Xb,
    const int* __restrict__ perm, const int* __restrict__ base,
    const float* __restrict__ sums, const int* __restrict__ counts,
    float* __restrict__ sumq) {
  __shared__ float wacc[4];
  const int g = blockIdx.x >> 3;
  const int s = blockIdx.x & (SPLIT - 1);
  const int t = threadIdx.x;
  const int w = t >> 6;
  const int lane = t & 63;
  const int start = base[g], end = base[g + 1];
  const int nviews = 2 * (end - start);
  const float invc = 1.0f / (float)counts[g];
  const float* sp = sums + g * DN + lane * 8;
  float4 c0 = *(const float4*)sp;
  float4 c1 = *(const float4*)(sp + 4);
  const float cs[8] = {c0.x * invc, c0.y * invc, c0.z * invc, c0.w * invc,
                       c1.x * invc, c1.y * invc, c1.z * invc, c1.w * invc};
  float q = 0.f;
  const int vs = s * 4 + w;   // virtual split 0..31
  for (int j = vs; j < nviews; j += SPLIT * 4) {
    const int idx = perm[start + (j >> 1)];
    const int row = idx + (j & 1) * BN;
    int4 chunk = *(const int4*)(Xb + (size_t)row * DN + lane * 8);
    const ushort* us = (const ushort*)&chunk;
    float ss = 0.f;
#pragma unroll
    for (int k = 0; k < 8; ++k) {
      float diff = bf2f(us[k]) - cs[k];
      ss += diff * diff;
    }
#pragma unroll
    for (int off = 32; off > 0; off >>= 1) ss += __shfl_down(ss, off, 64);
    if (lane == 0) q += sqrtf(sqrtf(ss));
  }
  if (lane == 0) wacc[w] = q;
  __syncthreads();
  if (t == 0) atomAddF(&sumq[g], wacc[0] + wacc[1] + wacc[2] + wacc[3]);
}

// ---- k4: density -> invd ----
__global__ __launch_bounds__(256) void k4_density(const float* __restrict__ sumq,
    const int* __restrict__ counts, float* __restrict__ invd) {
  __shared__ float sv[256];
  __shared__ float st[256];
  const int t = threadIdx.x;
  const int cnt = counts[t];
  const bool valid = cnt > 1;
  float dens = 0.f;
  if (valid) dens = (sumq[t] / (float)cnt) / logf((float)cnt + 10.f);
  sv[t] = valid ? dens : -INFINITY;
  __syncthreads();
  for (int s = 128; s > 0; s >>= 1) {
    if (t < s) sv[t] = fmaxf(sv[t], sv[t + s]);
    __syncthreads();
  }
  const float dmax = sv[0];
  __syncthreads();
  const float d0 = valid ? dens : dmax;
  sv[t] = d0;
  __syncthreads();
  int rank = 0;
  for (int j = 0; j < 256; ++j) {
    float vj = sv[j];
    rank += (vj < d0) || (vj == d0 && j < t);
  }
  st[rank] = d0;
  __syncthreads();
  const float q10 = 0.5f * (st[25] + st[26]);
  const float q90 = 0.5f * (st[229] + st[230]);
  const float dc = fminf(fmaxf(d0, q10), q90);
  sv[t] = dc;
  __syncthreads();
  for (int s = 128; s > 0; s >>= 1) {
    if (t < s) sv[t] += sv[t + s];
    __syncthreads();
  }
  const float mean = sv[0] * (1.0f / 256.f);
  invd[t] = mean / (0.1f * dc);
}

// ---- k5: MFMA GEMM (128 rows x 256 groups, K=512) + fused softmax loss ----
// global_load_lds staging, unpadded 128B rows + XOR-swizzled chunk layout.
#define TAB (128 * 128)   // A tile bytes
#define TBB (256 * 128)   // B tile bytes
__global__ __launch_bounds__(256, 3) void k5_mfma(const ushort* __restrict__ Xb,
    const ushort* __restrict__ centB, const int* __restrict__ subject,
    const int* __restrict__ labels, const float* __restrict__ invd,
    float* __restrict__ losssum) {
  __shared__ char smem[TAB + TBB + 1024];
  char* ldsA = smem;                 // [128 rows][128B, swizzled]
  char* ldsB = smem + TAB;           // [256 rows][128B, swizzled]
  float* maxbuf = (float*)smem;      // epilogue aliases ldsA: [4][128]
  float* gmax = (float*)(smem + 2048);    // [128]
  float* ebuf = (float*)(smem + 2560);    // [4][128]
  float* zbuf = (float*)(smem + 4608);    // [4][128]
  int* labs = (int*)(smem + TAB + TBB);
  int* subs = labs + 128;

  const int t = threadIdx.x;
  const int w = t >> 6;
  const int lane = t & 63;
  const int quad = lane >> 4;
  const int n16 = lane & 15;
  const int li = lane >> 3;          // row within an 8-row DMA chunk
  const int lc = lane & 7;           // lds slot chunk
  const int srcc = lc ^ li;          // swizzled source chunk
  const int rowbase = blockIdx.x * 128;

  if (t < 128) {
    int b = (rowbase + t) & (BN - 1);
    labs[t] = labels[b];
    subs[t] = subject[b];
  }

  f32x4 acc[8][4];
#pragma unroll
  for (int mt = 0; mt < 8; ++mt)
#pragma unroll
    for (int nt = 0; nt < 4; ++nt) acc[mt][nt] = (f32x4){0.f, 0.f, 0.f, 0.f};

  const ushort* Arow = Xb + (size_t)rowbase * DN;

  for (int k0 = 0; k0 < DN; k0 += 64) {
    __syncthreads();
#pragma unroll
    for (int q = 0; q < 4; ++q) {
      const int r0 = w * 32 + q * 8;
      async16(Arow + (size_t)(r0 + li) * DN + k0 + srcc * 8, ldsA + r0 * 128);
    }
#pragma unroll
    for (int q = 0; q < 8; ++q) {
      const int g0 = w * 64 + q * 8;
      async16(centB + (size_t)(g0 + li) * DN + k0 + srcc * 8, ldsB + g0 * 128);
    }
    __syncthreads();
#pragma unroll
    for (int s = 0; s < 2; ++s) {
      const int csw = ((s * 4 + quad) ^ (n16 & 7)) * 16;
      bf16x8 bfr[4];
#pragma unroll
      for (int nt = 0; nt < 4; ++nt) {
        int g = w * 64 + nt * 16 + n16;
        bfr[nt] = *(bf16x8*)(ldsB + g * 128 + csw);
      }
#pragma unroll
      for (int mt = 0; mt < 8; ++mt) {
        bf16x8 afr = *(bf16x8*)(ldsA + (mt * 16 + n16) * 128 + csw);
#pragma unroll
        for (int nt = 0; nt < 4; ++nt)
          acc[mt][nt] = __builtin_amdgcn_mfma_f32_16x16x32_bf16(afr, bfr[nt], acc[mt][nt], 0, 0, 0);
      }
    }
  }

  float iv[4];
#pragma unroll
  for (int nt = 0; nt < 4; ++nt) iv[nt] = invd[w * 64 + nt * 16 + n16];

  __syncthreads();

#pragma unroll
  for (int mt = 0; mt < 8; ++mt) {
#pragma unroll
    for (int r = 0; r < 4; ++r) {
      float mm = -INFINITY;
#pragma unroll
      for (int nt = 0; nt < 4; ++nt) mm = fmaxf(mm, acc[mt][nt][r] * iv[nt]);
#pragma unroll
      for (int off = 1; off < 16; off <<= 1) mm = fmaxf(mm, __shfl_xor(mm, off, 64));
      if (n16 == 0) maxbuf[w * 128 + mt * 16 + quad * 4 + r] = mm;
    }
  }
  __syncthreads();
  if (t < 128)
    gmax[t] = fmaxf(fmaxf(maxbuf[t], maxbuf[128 + t]),
                    fmaxf(maxbuf[256 + t], maxbuf[384 + t]));
  __syncthreads();

#pragma unroll
  for (int mt = 0; mt < 8; ++mt) {
#pragma unroll
    for (int r = 0; r < 4; ++r) {
      const int row = mt * 16 + quad * 4 + r;
      const float gm = gmax[row];
      const int lab = labs[row];
      const int sub = subs[row];
      float e = 0.f, z = 0.f;
      if ((n16 & 7) == lab) {
#pragma unroll
        for (int nt = 0; nt < 4; ++nt) {
          int gdiv8 = w * 8 + nt * 2 + (n16 >> 3);
          if (gdiv8 != sub) {
            float sv = acc[mt][nt][r] * iv[nt] - gm;
            e += expf(sv);
            z += sv;
          }
        }
      }
#pragma unroll
      for (int off = 1; off < 16; off <<= 1) {
        e += __shfl_xor(e, off, 64);
        z += __shfl_xor(z, off, 64);
      }
      if (n16 == 0) {
        ebuf[w * 128 + row] = e;
        zbuf[w * 128 + row] = z;
      }
    }
  }
  __syncthreads();

  float lsum = 0.f;
  if (t < 128) {
    float e = ebuf[t] + ebuf[128 + t] + ebuf[256 + t] + ebuf[384 + t];
    float z = zbuf[t] + zbuf[128 + t] + zbuf[256 + t] + zbuf[384 + t];
    lsum = logf(225.f + e) - z * (1.0f / 31.0f);
  }
#pragma unroll
  for (int off = 32; off > 0; off >>= 1) lsum += __shfl_down(lsum, off, 64);
  if (lane == 0 && lsum != 0.f) atomAddF(losssum, lsum);
}

// ---- k6: final mean ----
__global__ void k6_final(const float* __restrict__ losssum, float* __restrict__ out) {
  out[0] = losssum[0] * (1.0f / (float)N2);
}

extern "C" void kernel_launch(void* const* d_in, const int* in_sizes, int n_in,
                              void* d_out, int out_size, void* d_ws, size_t ws_size,
                              hipStream_t stream) {
  const float* X = (const float*)d_in[0];
  const int* subject = (const int*)d_in[1];
  const int* labels = (const int*)d_in[2];
  char* ws = (char*)d_ws;
  ushort* Xb = (ushort*)(ws + OFF_XBF);
  float* partial = (float*)(ws + OFF_PART);
  float* sums = (float*)(ws + OFF_SUMS);
  ushort* centB = (ushort*)(ws + OFF_CENTB);
  int* gid = (int*)(ws + OFF_GID);
  int* perm = (int*)(ws + OFF_PERM);
  int* basep = (int*)(ws + OFF_BASE);
  int* offw = (int*)(ws + OFF_OFFW);
  int* counts = (int*)(ws + OFF_COUNTS);
  float* sumq = (float*)(ws + OFF_SUMQ);
  float* invd = (float*)(ws + OFF_INVD);
  float* losssum = (float*)(ws + OFF_LOSS);

  hipMemsetAsync(ws + ZERO_OFF, 0, ZERO_BYTES, stream);
  k0_gid<<<BN / 1024, 256, 0, stream>>>(subject, labels, gid, counts);
  k0b_scan<<<1, 256, 0, stream>>>(counts, basep, offw);
  k0c_scatter<<<BN / 1024, 256, 0, stream>>>(gid, offw, perm);
  k1_sums<<<KN * SPLIT, 256, 0, stream>>>(X, perm, basep, Xb, partial);
  k1b_cent<<<(KN * DN) / 256, 256, 0, stream>>>(partial, counts, sums, centB);
  k3_dist<<<KN * SPLIT, 256, 0, stream>>>(Xb, perm, basep, sums, counts, sumq);
  k4_density<<<1, 256, 0, stream>>>(sumq, counts, invd);
  k5_mfma<<<N2 / 128, 256, 0, stream>>>(Xb, centB, subject, labels, invd, losssum);
  k6_final<<<1, 1, 0, stream>>>(losssum, (float*)d_out);
}

// Round 9
// 296.508 us; speedup vs baseline: 1.1010x; 1.1010x over previous
//
#include <hip/hip_runtime.h>
#include <math.h>

// Problem constants
#define BN 32768
#define DN 512
#define SN 32
#define LN 8
#define KN 256
#define N2 65536   // 2*BN
#define SPLIT 8    // blocks per group in k1/k3

typedef __attribute__((ext_vector_type(8))) short bf16x8;
typedef __attribute__((ext_vector_type(4))) float f32x4;

// workspace layout (byte offsets)
#define OFF_XBF     0ull            // ushort[N2*DN]            67108864
#define OFF_PART    67108864ull     // float[SPLIT*KN*DN]        4194304
#define OFF_SUMS    71303168ull     // float[KN*DN]               524288
#define OFF_CENTB   71827456ull     // ushort[KN*DN]              262144
#define OFF_GID     72089600ull     // int[BN]                    131072
#define OFF_PERM    72220672ull     // int[BN]                    131072
#define OFF_BASE    72351744ull     // int[KN+1]
#define OFF_OFFW    72352772ull     // int[KN]
#define OFF_COUNTS  72353796ull     // int[KN]
#define OFF_SUMQ    72354820ull     // float[KN]
#define OFF_INVD    72355844ull     // float[KN]
#define OFF_LOSS    72356868ull     // float[1]
#define ZERO_OFF    OFF_COUNTS
#define ZERO_BYTES  (72356872ull - OFF_COUNTS)

__device__ __forceinline__ float atomAddF(float* p, float v) {
  return unsafeAtomicAdd(p, v);   // hw global_atomic_add_f32
}

__device__ __forceinline__ ushort f2bf(float x) {
  union { float f; unsigned u; } v; v.f = x;
  unsigned u = v.u;
  unsigned r = (u + 0x7fffu + ((u >> 16) & 1u)) >> 16;  // RNE
  return (ushort)r;
}

__device__ __forceinline__ float bf2f(ushort x) {
  union { unsigned u; float f; } v; v.u = ((unsigned)x) << 16;
  return v.f;
}

// async 16B/lane global->LDS DMA (lands at lds base + lane*16)
__device__ __forceinline__ void async16(const void* g, void* l) {
  __builtin_amdgcn_global_load_lds(
      (const __attribute__((address_space(1))) unsigned int*)g,
      (__attribute__((address_space(3))) unsigned int*)l, 16, 0, 0);
}

// ---- k0a: gid + counts histogram ----
__global__ __launch_bounds__(256) void k0_gid(const int* __restrict__ subject,
    const int* __restrict__ labels, int* __restrict__ gid, int* __restrict__ counts) {
  __shared__ int hist[KN];
  hist[threadIdx.x] = 0;
  __syncthreads();
  const int b0 = blockIdx.x * 1024;
  for (int i = threadIdx.x; i < 1024; i += 256) {
    int b = b0 + i;
    int g = subject[b] * LN + labels[b];
    gid[b] = g;
    atomicAdd(&hist[g], 1);
  }
  __syncthreads();
  if (hist[threadIdx.x]) atomicAdd(&counts[threadIdx.x], 2 * hist[threadIdx.x]);
}

// ---- k0b: exclusive scan of per-group row counts -> base, offw ----
__global__ __launch_bounds__(256) void k0b_scan(const int* __restrict__ counts,
    int* __restrict__ base, int* __restrict__ offw) {
  __shared__ int sh[KN];
  const int t = threadIdx.x;
  const int h = counts[t] >> 1;   // rows (not x2 views)
  sh[t] = h;
  __syncthreads();
  for (int d = 1; d < 256; d <<= 1) {
    int add = (t >= d) ? sh[t - d] : 0;
    __syncthreads();
    sh[t] += add;
    __syncthreads();
  }
  const int excl = sh[t] - h;
  base[t] = excl;
  offw[t] = excl;
  if (t == 255) base[256] = sh[255];
}

// ---- k0c: counting-sort scatter -> perm, LDS-aggregated ----
// 32 blocks x 1024 rows; local rank via LDS atomic return value (within-group
// order is irrelevant downstream), ONE global atomic per (block, group).
__global__ __launch_bounds__(256) void k0c_scatter(const int* __restrict__ gid,
    int* __restrict__ offw, int* __restrict__ perm) {
  __shared__ int lhist[KN];
  __shared__ int lbase[KN];
  const int t = threadIdx.x;
  const int b0 = blockIdx.x * 1024;
  lhist[t] = 0;
  __syncthreads();
  int g[4], lr[4];
#pragma unroll
  for (int k = 0; k < 4; ++k) {
    g[k] = gid[b0 + k * 256 + t];
    lr[k] = atomicAdd(&lhist[g[k]], 1);
  }
  __syncthreads();
  const int h = lhist[t];
  if (h) lbase[t] = atomicAdd(&offw[t], h);
  __syncthreads();
#pragma unroll
  for (int k = 0; k < 4; ++k) {
    perm[lbase[g[k]] + lr[k]] = b0 + k * 256 + t;
  }
}

// ---- k1: sorted segment-reduce group sums + f32->bf16 conversion ----
// Wave-parallel: each wave owns an independent row stream (32 streams/group).
__global__ __launch_bounds__(256) void k1_sums(const float* __restrict__ X,
    const int* __restrict__ perm, const int* __restrict__ base,
    ushort* __restrict__ Xb, float* __restrict__ partial) {
  __shared__ float buf[4 * 512];
  const int g = blockIdx.x >> 3;
  const int s = blockIdx.x & (SPLIT - 1);
  const int t = threadIdx.x;
  const int w = t >> 6;
  const int lane = t & 63;
  const int start = base[g], end = base[g + 1];
  const int vs = s * 4 + w;              // stream 0..31

  float4 a0 = {0.f, 0.f, 0.f, 0.f};
  float4 a1 = {0.f, 0.f, 0.f, 0.f};

  int i = start + vs;
  if (i < end) {
    int idx = perm[i];
    const float* bp = X + (size_t)idx * 1024 + lane * 4;
    float4 x0 = *(const float4*)(bp);
    float4 x1 = *(const float4*)(bp + 256);
    float4 x2 = *(const float4*)(bp + 512);
    float4 x3 = *(const float4*)(bp + 768);
    while (true) {
      const int inext = i + 32;
      int idxn = idx;
      float4 y0 = x0, y1 = x1, y2 = x2, y3 = x3;
      if (inext < end) {
        idxn = perm[inext];
        const float* bn = X + (size_t)idxn * 1024 + lane * 4;
        y0 = *(const float4*)(bn);
        y1 = *(const float4*)(bn + 256);
        y2 = *(const float4*)(bn + 512);
        y3 = *(const float4*)(bn + 768);
      }
      a0.x += x0.x + x2.x; a0.y += x0.y + x2.y;
      a0.z += x0.z + x2.z; a0.w += x0.w + x2.w;
      a1.x += x1.x + x3.x; a1.y += x1.y + x3.y;
      a1.z += x1.z + x3.z; a1.w += x1.w + x3.w;
      ushort* xb0 = Xb + (size_t)idx * DN + lane * 4;
      ushort* xb1 = Xb + (size_t)(idx + BN) * DN + lane * 4;
      *(ushort4*)(xb0)       = (ushort4){f2bf(x0.x), f2bf(x0.y), f2bf(x0.z), f2bf(x0.w)};
      *(ushort4*)(xb0 + 256) = (ushort4){f2bf(x1.x), f2bf(x1.y), f2bf(x1.z), f2bf(x1.w)};
      *(ushort4*)(xb1)       = (ushort4){f2bf(x2.x), f2bf(x2.y), f2bf(x2.z), f2bf(x2.w)};
      *(ushort4*)(xb1 + 256) = (ushort4){f2bf(x3.x), f2bf(x3.y), f2bf(x3.z), f2bf(x3.w)};
      if (inext >= end) break;
      i = inext; idx = idxn; x0 = y0; x1 = y1; x2 = y2; x3 = y3;
    }
  }
  *(float4*)&buf[w * 512 + lane * 4] = a0;
  *(float4*)&buf[w * 512 + 256 + lane * 4] = a1;
  __syncthreads();
  if (t < 128) {
    float4 r = {0.f, 0.f, 0.f, 0.f};
#pragma unroll
    for (int ww = 0; ww < 4; ++ww) {
      float4 v = *(float4*)&buf[ww * 512 + t * 4];
      r.x += v.x; r.y += v.y; r.z += v.z; r.w += v.w;
    }
    *(float4*)&partial[((size_t)s * KN + g) * DN + t * 4] = r;
  }
}

// ---- k1b: reduce split partials -> sums + bf16 centroids ----
__global__ __launch_bounds__(256) void k1b_cent(const float* __restrict__ partial,
    const int* __restrict__ counts, float* __restrict__ sums,
    ushort* __restrict__ centB) {
  const int i = blockIdx.x * 256 + threadIdx.x;   // over KN*DN, [g][d]
  const int g = i >> 9;
  float ss = 0.f;
#pragma unroll
  for (int s = 0; s < SPLIT; ++s) ss += partial[(size_t)s * (KN * DN) + i];
  sums[i] = ss;
  centB[i] = f2bf(ss / (float)counts[g]);
}

// ---- k3: group-per-block distance^0.25 accumulation, 1 atomic/block ----
__global__ __launch_bounds__(256) void k3_dist(const ushort* __restrict__ Xb,
    const int* __restrict__ perm, const int* __restrict__ base,
    const float* __restrict__ sums, const int* __restrict__ counts,
    float* __restrict__ sumq) {
  __shared__ float wacc[4];
  const int g = blockIdx.x >> 3;
  const int s = blockIdx.x & (SPLIT - 1);
  const int t = threadIdx.x;
  const int w = t >> 6;
  const int lane = t & 63;
  const int start = base[g], end = base[g + 1];
  const int nviews = 2 * (end - start);
  const float invc = 1.0f / (float)counts[g];
  const float* sp = sums + g * DN + lane * 8;
  float4 c0 = *(const float4*)sp;
  float4 c1 = *(const float4*)(sp + 4);
  const float cs[8] = {c0.x * invc, c0.y * invc, c0.z * invc, c0.w * invc,
                       c1.x * invc, c1.y * invc, c1.z * invc, c1.w * invc};
  float q = 0.f;
  const int vs = s * 4 + w;   // virtual split 0..31
  for (int j = vs; j < nviews; j += SPLIT * 4) {
    const int idx = perm[start + (j >> 1)];
    const int row = idx + (j & 1) * BN;
    int4 chunk = *(const int4*)(Xb + (size_t)row * DN + lane * 8);
    const ushort* us = (const ushort*)&chunk;
    float ss = 0.f;
#pragma unroll
    for (int k = 0; k < 8; ++k) {
      float diff = bf2f(us[k]) - cs[k];
      ss += diff * diff;
    }
#pragma unroll
    for (int off = 32; off > 0; off >>= 1) ss += __shfl_down(ss, off, 64);
    if (lane == 0) q += sqrtf(sqrtf(ss));
  }
  if (lane == 0) wacc[w] = q;
  __syncthreads();
  if (t == 0) atomAddF(&sumq[g], wacc[0] + wacc[1] + wacc[2] + wacc[3]);
}

// ---- k4: density -> invd ----
__global__ __launch_bounds__(256) void k4_density(const float* __restrict__ sumq,
    const int* __restrict__ counts, float* __restrict__ invd) {
  __shared__ float sv[256];
  __shared__ float st[256];
  const int t = threadIdx.x;
  const int cnt = counts[t];
  const bool valid = cnt > 1;
  float dens = 0.f;
  if (valid) dens = (sumq[t] / (float)cnt) / logf((float)cnt + 10.f);
  sv[t] = valid ? dens : -INFINITY;
  __syncthreads();
  for (int s = 128; s > 0; s >>= 1) {
    if (t < s) sv[t] = fmaxf(sv[t], sv[t + s]);
    __syncthreads();
  }
  const float dmax = sv[0];
  __syncthreads();
  const float d0 = valid ? dens : dmax;
  sv[t] = d0;
  __syncthreads();
  int rank = 0;
  for (int j = 0; j < 256; ++j) {
    float vj = sv[j];
    rank += (vj < d0) || (vj == d0 && j < t);
  }
  st[rank] = d0;
  __syncthreads();
  const float q10 = 0.5f * (st[25] + st[26]);
  const float q90 = 0.5f * (st[229] + st[230]);
  const float dc = fminf(fmaxf(d0, q10), q90);
  sv[t] = dc;
  __syncthreads();
  for (int s = 128; s > 0; s >>= 1) {
    if (t < s) sv[t] += sv[t + s];
    __syncthreads();
  }
  const float mean = sv[0] * (1.0f / 256.f);
  invd[t] = mean / (0.1f * dc);
}

// ---- k5: MFMA GEMM (128 rows x 256 groups, K=512) + fused softmax loss ----
// global_load_lds staging, unpadded 128B rows + XOR-swizzled chunk layout.
// NOTE: (256,2) is required — (256,3) caps VGPRs at ~170 < 128 acc + staging
// and spills accumulators to scratch (R8: WRITE_SIZE 64MB, dur 136us).
#define TAB (128 * 128)   // A tile bytes
#define TBB (256 * 128)   // B tile bytes
__global__ __launch_bounds__(256, 2) void k5_mfma(const ushort* __restrict__ Xb,
    const ushort* __restrict__ centB, const int* __restrict__ subject,
    const int* __restrict__ labels, const float* __restrict__ invd,
    float* __restrict__ losssum) {
  __shared__ char smem[TAB + TBB + 1024];
  char* ldsA = smem;                 // [128 rows][128B, swizzled]
  char* ldsB = smem + TAB;           // [256 rows][128B, swizzled]
  float* maxbuf = (float*)smem;      // epilogue aliases ldsA: [4][128]
  float* gmax = (float*)(smem + 2048);    // [128]
  float* ebuf = (float*)(smem + 2560);    // [4][128]
  float* zbuf = (float*)(smem + 4608);    // [4][128]
  int* labs = (int*)(smem + TAB + TBB);
  int* subs = labs + 128;

  const int t = threadIdx.x;
  const int w = t >> 6;
  const int lane = t & 63;
  const int quad = lane >> 4;
  const int n16 = lane & 15;
  const int li = lane >> 3;          // row within an 8-row DMA chunk
  const int lc = lane & 7;           // lds slot chunk
  const int srcc = lc ^ li;          // swizzled source chunk
  const int rowbase = blockIdx.x * 128;

  if (t < 128) {
    int b = (rowbase + t) & (BN - 1);
    labs[t] = labels[b];
    subs[t] = subject[b];
  }

  f32x4 acc[8][4];
#pragma unroll
  for (int mt = 0; mt < 8; ++mt)
#pragma unroll
    for (int nt = 0; nt < 4; ++nt) acc[mt][nt] = (f32x4){0.f, 0.f, 0.f, 0.f};

  const ushort* Arow = Xb + (size_t)rowbase * DN;

  for (int k0 = 0; k0 < DN; k0 += 64) {
    __syncthreads();
#pragma unroll
    for (int q = 0; q < 4; ++q) {
      const int r0 = w * 32 + q * 8;
      async16(Arow + (size_t)(r0 + li) * DN + k0 + srcc * 8, ldsA + r0 * 128);
    }
#pragma unroll
    for (int q = 0; q < 8; ++q) {
      const int g0 = w * 64 + q * 8;
      async16(centB + (size_t)(g0 + li) * DN + k0 + srcc * 8, ldsB + g0 * 128);
    }
    __syncthreads();
#pragma unroll
    for (int s = 0; s < 2; ++s) {
      const int csw = ((s * 4 + quad) ^ (n16 & 7)) * 16;
      bf16x8 bfr[4];
#pragma unroll
      for (int nt = 0; nt < 4; ++nt) {
        int g = w * 64 + nt * 16 + n16;
        bfr[nt] = *(bf16x8*)(ldsB + g * 128 + csw);
      }
#pragma unroll
      for (int mt = 0; mt < 8; ++mt) {
        bf16x8 afr = *(bf16x8*)(ldsA + (mt * 16 + n16) * 128 + csw);
#pragma unroll
        for (int nt = 0; nt < 4; ++nt)
          acc[mt][nt] = __builtin_amdgcn_mfma_f32_16x16x32_bf16(afr, bfr[nt], acc[mt][nt], 0, 0, 0);
      }
    }
  }

  float iv[4];
#pragma unroll
  for (int nt = 0; nt < 4; ++nt) iv[nt] = invd[w * 64 + nt * 16 + n16];

  __syncthreads();

#pragma unroll
  for (int mt = 0; mt < 8; ++mt) {
#pragma unroll
    for (int r = 0; r < 4; ++r) {
      float mm = -INFINITY;
#pragma unroll
      for (int nt = 0; nt < 4; ++nt) mm = fmaxf(mm, acc[mt][nt][r] * iv[nt]);
#pragma unroll
      for (int off = 1; off < 16; off <<= 1) mm = fmaxf(mm, __shfl_xor(mm, off, 64));
      if (n16 == 0) maxbuf[w * 128 + mt * 16 + quad * 4 + r] = mm;
    }
  }
  __syncthreads();
  if (t < 128)
    gmax[t] = fmaxf(fmaxf(maxbuf[t], maxbuf[128 + t]),
                    fmaxf(maxbuf[256 + t], maxbuf[384 + t]));
  __syncthreads();

#pragma unroll
  for (int mt = 0; mt < 8; ++mt) {
#pragma unroll
    for (int r = 0; r < 4; ++r) {
      const int row = mt * 16 + quad * 4 + r;
      const float gm = gmax[row];
      const int lab = labs[row];
      const int sub = subs[row];
      float e = 0.f, z = 0.f;
      if ((n16 & 7) == lab) {
#pragma unroll
        for (int nt = 0; nt < 4; ++nt) {
          int gdiv8 = w * 8 + nt * 2 + (n16 >> 3);
          if (gdiv8 != sub) {
            float sv = acc[mt][nt][r] * iv[nt] - gm;
            e += expf(sv);
            z += sv;
          }
        }
      }
#pragma unroll
      for (int off = 1; off < 16; off <<= 1) {
        e += __shfl_xor(e, off, 64);
        z += __shfl_xor(z, off, 64);
      }
      if (n16 == 0) {
        ebuf[w * 128 + row] = e;
        zbuf[w * 128 + row] = z;
      }
    }
  }
  __syncthreads();

  float lsum = 0.f;
  if (t < 128) {
    float e = ebuf[t] + ebuf[128 + t] + ebuf[256 + t] + ebuf[384 + t];
    float z = zbuf[t] + zbuf[128 + t] + zbuf[256 + t] + zbuf[384 + t];
    lsum = logf(225.f + e) - z * (1.0f / 31.0f);
  }
#pragma unroll
  for (int off = 32; off > 0; off >>= 1) lsum += __shfl_down(lsum, off, 64);
  if (lane == 0 && lsum != 0.f) atomAddF(losssum, lsum);
}

// ---- k6: final mean ----
__global__ void k6_final(const float* __restrict__ losssum, float* __restrict__ out) {
  out[0] = losssum[0] * (1.0f / (float)N2);
}

extern "C" void kernel_launch(void* const* d_in, const int* in_sizes, int n_in,
                              void* d_out, int out_size, void* d_ws, size_t ws_size,
                              hipStream_t stream) {
  const float* X = (const float*)d_in[0];
  const int* subject = (const int*)d_in[1];
  const int* labels = (const int*)d_in[2];
  char* ws = (char*)d_ws;
  ushort* Xb = (ushort*)(ws + OFF_XBF);
  float* partial = (float*)(ws + OFF_PART);
  float* sums = (float*)(ws + OFF_SUMS);
  ushort* centB = (ushort*)(ws + OFF_CENTB);
  int* gid = (int*)(ws + OFF_GID);
  int* perm = (int*)(ws + OFF_PERM);
  int* basep = (int*)(ws + OFF_BASE);
  int* offw = (int*)(ws + OFF_OFFW);
  int* counts = (int*)(ws + OFF_COUNTS);
  float* sumq = (float*)(ws + OFF_SUMQ);
  float* invd = (float*)(ws + OFF_INVD);
  float* losssum = (float*)(ws + OFF_LOSS);

  hipMemsetAsync(ws + ZERO_OFF, 0, ZERO_BYTES, stream);
  k0_gid<<<BN / 1024, 256, 0, stream>>>(subject, labels, gid, counts);
  k0b_scan<<<1, 256, 0, stream>>>(counts, basep, offw);
  k0c_scatter<<<BN / 1024, 256, 0, stream>>>(gid, offw, perm);
  k1_sums<<<KN * SPLIT, 256, 0, stream>>>(X, perm, basep, Xb, partial);
  k1b_cent<<<(KN * DN) / 256, 256, 0, stream>>>(partial, counts, sums, centB);
  k3_dist<<<KN * SPLIT, 256, 0, stream>>>(Xb, perm, basep, sums, counts, sumq);
  k4_density<<<1, 256, 0, stream>>>(sumq, counts, invd);
  k5_mfma<<<N2 / 128, 256, 0, stream>>>(Xb, centB, subject, labels, invd, losssum);
  k6_final<<<1, 1, 0, stream>>>(losssum, (float*)d_out);
}